// Round 3
// baseline (403.575 us; speedup 1.0000x reference)
//
#include <hip/hip_runtime.h>
#include <hip/hip_bf16.h>
#include <cstdint>

// Problem constants
#define S_FRAMES 128
#define HW       50176            // 224*224
#define NGRP     12544            // HW/4 float4 groups per frame
#define GDIM     48
#define VWORDS   3456             // 48^3 / 32 bits
#define NBINS    4096
#define CAP      512
#define KSEL     16
#define NWPT     14               // ceil(3456/256) occ words per thread in greedy

// workspace layout (in 32-bit words)
#define OCCA_OFF  0u                          // 128 * 3456 words (part 0 bitmaps)
#define OCCB_OFF  (128u*3456u)                // 442368: part 1 bitmaps
#define KEY_OFF   (2u*128u*3456u)             // 884736: 16 words (argmax keys)
#define BAR_OFF   (KEY_OFF + 16u)             // 884752: 2 words (barrier cnt, gen)
#define MM_OFF    (KEY_OFF + 32u)             // 884768: 64 slots x 16 words (64B each)
#define PCT_OFF   (MM_OFF + 64u*16u)          // 885792: 128 floats
#define ZERO_OFF  KEY_OFF
#define ZERO_WORDS (PCT_OFF - KEY_OFF)        // keys + barrier + mm slots

__device__ __forceinline__ unsigned fkey(float f) {
    unsigned u = __float_as_uint(f);
    return (u & 0x80000000u) ? ~u : (u | 0x80000000u);
}
__device__ __forceinline__ float funkey(unsigned k) {
    unsigned u = (k & 0x80000000u) ? (k & 0x7fffffffu) : ~k;
    return __uint_as_float(u);
}

// ---------------------------------------------------------------------------
// Pass A: exact per-frame median (jnp.quantile 0.5 linear) via histogram select
// grid: 128 blocks (one per frame), 1024 threads, float4 loads both passes
// ---------------------------------------------------------------------------
__global__ __launch_bounds__(1024) void pct_kernel(const float* __restrict__ conf,
                                                   float* __restrict__ pct) {
    const int s = blockIdx.x;
    const int tid = threadIdx.x;
    const float4* c4 = (const float4*)(conf + (size_t)s * HW);

    __shared__ unsigned hist[NBINS];
    __shared__ unsigned ps[1024];
    __shared__ float    list[CAP];
    __shared__ unsigned cnt;
    __shared__ int      rbin[2];
    __shared__ unsigned rcum[2];
    __shared__ float    ab[2];

    for (int b = tid; b < NBINS; b += 1024) hist[b] = 0;
    if (tid == 0) cnt = 0;
    __syncthreads();

    for (int g = tid; g < NGRP; g += 1024) {
        float4 v = c4[g];
        int b0 = min(max((int)(v.x * 4096.0f), 0), NBINS - 1);
        int b1 = min(max((int)(v.y * 4096.0f), 0), NBINS - 1);
        int b2 = min(max((int)(v.z * 4096.0f), 0), NBINS - 1);
        int b3 = min(max((int)(v.w * 4096.0f), 0), NBINS - 1);
        atomicAdd(&hist[b0], 1u); atomicAdd(&hist[b1], 1u);
        atomicAdd(&hist[b2], 1u); atomicAdd(&hist[b3], 1u);
    }
    __syncthreads();

    // chunk sums (4 bins/thread) + inclusive scan over 1024 chunks
    unsigned chunk = hist[tid * 4] + hist[tid * 4 + 1] + hist[tid * 4 + 2] + hist[tid * 4 + 3];
    ps[tid] = chunk;
    __syncthreads();
    for (int off = 1; off < 1024; off <<= 1) {
        unsigned v = (tid >= off) ? ps[tid - off] : 0u;
        __syncthreads();
        ps[tid] += v;
        __syncthreads();
    }
    unsigned excl = ps[tid] - chunk;

    const unsigned R0 = 25087u, R1 = 25088u;  // 0.5*(50176-1) = 25087.5
#pragma unroll
    for (int r = 0; r < 2; r++) {
        unsigned rr = r ? R1 : R0;
        if (rr >= excl && rr < excl + chunk) {
            unsigned cum = excl;
            for (int j = 0; j < 4; j++) {
                unsigned h = hist[tid * 4 + j];
                if (rr < cum + h) { rbin[r] = tid * 4 + j; rcum[r] = cum; break; }
                cum += h;
            }
        }
    }
    __syncthreads();

    const int blo = rbin[0], bhi = rbin[1];
    const unsigned cumLo = rcum[0];

    for (int g = tid; g < NGRP; g += 1024) {
        float4 v = c4[g];
        float vv[4] = {v.x, v.y, v.z, v.w};
#pragma unroll
        for (int j = 0; j < 4; j++) {
            int b = min(max((int)(vv[j] * 4096.0f), 0), NBINS - 1);
            if (b >= blo && b <= bhi) {
                unsigned pos = atomicAdd(&cnt, 1u);
                if (pos < CAP) list[pos] = vv[j];
            }
        }
    }
    __syncthreads();

    const int n = (int)min(cnt, (unsigned)CAP);
    const int r0 = (int)(R0 - cumLo), r1 = (int)(R1 - cumLo);
    for (int e = tid; e < n; e += 1024) {
        float x = list[e];
        int rank = 0;
        for (int j = 0; j < n; j++) {
            float y = list[j];
            rank += (y < x) || (y == x && j < e);   // stable rank
        }
        if (rank == r0) ab[0] = x;
        if (rank == r1) ab[1] = x;
    }
    __syncthreads();
    if (tid == 0) pct[s] = 0.5f * ab[0] + 0.5f * ab[1];
}

// ---------------------------------------------------------------------------
// Pass B: global min/max over valid points. grid (49,128) x 256, 4 pts/thread.
// All-atomicMax encoding: min(x) tracked as max over fkey(-x). 64 slots of one
// cache line each to kill same-line atomic serialization.
// ---------------------------------------------------------------------------
__global__ __launch_bounds__(256) void minmax_kernel(const float* __restrict__ wp,
                                                     const float* __restrict__ conf,
                                                     const float* __restrict__ pct,
                                                     unsigned* __restrict__ ws) {
    const int s = blockIdx.y;
    const int tid = threadIdx.x;
    const int gidx = blockIdx.x * 256 + tid;        // [0, 12544)
    const float pc = pct[s];
    const size_t base = (size_t)s * HW;

    const float4 cf = ((const float4*)(conf + base))[gidx];
    const float4* wp4 = (const float4*)(wp + base * 3) + (size_t)gidx * 3;
    const float4 a = wp4[0], b = wp4[1], d = wp4[2];

    const float BIG = 3.402823466e38f;
    float mnx = BIG, mny = BIG, mnz = BIG;
    float mxx = -BIG, mxy = -BIG, mxz = -BIG;

    float px[4] = {a.x, a.w, b.z, d.y};
    float py[4] = {a.y, b.x, b.w, d.z};
    float pz[4] = {a.z, b.y, d.x, d.w};
    float cc[4] = {cf.x, cf.y, cf.z, cf.w};
#pragma unroll
    for (int j = 0; j < 4; j++) {
        bool v = (cc[j] > 0.1f) && (cc[j] >= pc);
        float x = v ? px[j] : BIG, y = v ? py[j] : BIG, z = v ? pz[j] : BIG;
        mnx = fminf(mnx, x); mny = fminf(mny, y); mnz = fminf(mnz, z);
        x = v ? px[j] : -BIG; y = v ? py[j] : -BIG; z = v ? pz[j] : -BIG;
        mxx = fmaxf(mxx, x); mxy = fmaxf(mxy, y); mxz = fmaxf(mxz, z);
    }
#pragma unroll
    for (int m = 32; m >= 1; m >>= 1) {
        mnx = fminf(mnx, __shfl_xor(mnx, m)); mny = fminf(mny, __shfl_xor(mny, m));
        mnz = fminf(mnz, __shfl_xor(mnz, m));
        mxx = fmaxf(mxx, __shfl_xor(mxx, m)); mxy = fmaxf(mxy, __shfl_xor(mxy, m));
        mxz = fmaxf(mxz, __shfl_xor(mxz, m));
    }
    __shared__ float red[4][6];
    if ((tid & 63) == 0) {
        int w = tid >> 6;
        red[w][0] = mnx; red[w][1] = mny; red[w][2] = mnz;
        red[w][3] = mxx; red[w][4] = mxy; red[w][5] = mxz;
    }
    __syncthreads();
    if (tid == 0) {
        float r0 = red[0][0], r1 = red[0][1], r2 = red[0][2];
        float r3 = red[0][3], r4 = red[0][4], r5 = red[0][5];
        for (int w = 1; w < 4; w++) {
            r0 = fminf(r0, red[w][0]); r1 = fminf(r1, red[w][1]); r2 = fminf(r2, red[w][2]);
            r3 = fmaxf(r3, red[w][3]); r4 = fmaxf(r4, red[w][4]); r5 = fmaxf(r5, red[w][5]);
        }
        unsigned* slot = ws + MM_OFF + (unsigned)((blockIdx.x + blockIdx.y * 49) & 63) * 16;
        atomicMax(slot + 0, fkey(-r0));   // min x  (as max of key(-x))
        atomicMax(slot + 1, fkey(-r1));
        atomicMax(slot + 2, fkey(-r2));
        atomicMax(slot + 3, fkey(r3));    // max x
        atomicMax(slot + 4, fkey(r4));
        atomicMax(slot + 5, fkey(r5));
    }
}

// ---------------------------------------------------------------------------
// Pass C: per-frame voxel occupancy. grid 256 (2 blocks/frame) x 512 threads.
// Each block plain-stores its half-frame bitmap to its own plane (occA/occB);
// greedy ORs the planes on load. Zero global atomics.
// ---------------------------------------------------------------------------
__global__ __launch_bounds__(512) void voxel_kernel(const float* __restrict__ wp,
                                                    const float* __restrict__ conf,
                                                    const float* __restrict__ pct,
                                                    unsigned* __restrict__ ws) {
    const int s = blockIdx.x >> 1;
    const int part = blockIdx.x & 1;
    const int tid = threadIdx.x;

    __shared__ unsigned bm[VWORDS];
    __shared__ float prm[4];  // pmx,pmy,pmz,vs
    for (int w = tid; w < VWORDS; w += 512) bm[w] = 0;

    if (tid < 64) {
        const unsigned* sl = ws + MM_OFF + (unsigned)tid * 16;
        unsigned k0 = sl[0], k1 = sl[1], k2 = sl[2], k3 = sl[3], k4 = sl[4], k5 = sl[5];
#pragma unroll
        for (int m = 32; m >= 1; m >>= 1) {
            k0 = max(k0, (unsigned)__shfl_xor((int)k0, m));
            k1 = max(k1, (unsigned)__shfl_xor((int)k1, m));
            k2 = max(k2, (unsigned)__shfl_xor((int)k2, m));
            k3 = max(k3, (unsigned)__shfl_xor((int)k3, m));
            k4 = max(k4, (unsigned)__shfl_xor((int)k4, m));
            k5 = max(k5, (unsigned)__shfl_xor((int)k5, m));
        }
        if (tid == 0) {
            float p0 = -funkey(k0), p1 = -funkey(k1), p2 = -funkey(k2);
            float d0 = funkey(k3) - p0, d1 = funkey(k4) - p1, d2 = funkey(k5) - p2;
            prm[0] = p0; prm[1] = p1; prm[2] = p2;
            prm[3] = fminf(d0, fminf(d1, d2)) / 20.0f;   // VOXEL_LAMBDA
        }
    }
    __syncthreads();

    const float pc = pct[s];
    const float pmx = prm[0], pmy = prm[1], pmz = prm[2], vs = prm[3];
    const size_t base = (size_t)s * HW;
    const float4* c4 = (const float4*)(conf + base);
    const float4* w4 = (const float4*)(wp + base * 3);

#pragma unroll 1
    for (int k = 0; k < 13; k++) {
        int gl = k * 512 + tid;                        // local group in half
        if (gl >= 6272) break;
        int g = part * 6272 + gl;
        float4 cf = c4[g];
        const float4* wg = w4 + (size_t)g * 3;
        float4 a = wg[0], b = wg[1], d = wg[2];
        float px[4] = {a.x, a.w, b.z, d.y};
        float py[4] = {a.y, b.x, b.w, d.z};
        float pz[4] = {a.z, b.y, d.x, d.w};
        float cc[4] = {cf.x, cf.y, cf.z, cf.w};
#pragma unroll
        for (int j = 0; j < 4; j++) {
            if (cc[j] > 0.1f && cc[j] >= pc) {
                int ix = min(max((int)floorf((px[j] - pmx) / vs), 0), GDIM - 1);
                int iy = min(max((int)floorf((py[j] - pmy) / vs), 0), GDIM - 1);
                int iz = min(max((int)floorf((pz[j] - pmz) / vs), 0), GDIM - 1);
                int vid = (ix * GDIM + iy) * GDIM + iz;
                atomicOr(&bm[vid >> 5], 1u << (vid & 31));
            }
        }
    }
    __syncthreads();

    unsigned* occ = ws + (part ? OCCB_OFF : OCCA_OFF) + (unsigned)s * VWORDS;
    for (int w = tid; w < VWORDS; w += 512) occ[w] = bm[w];
}

// ---------------------------------------------------------------------------
// Greedy max coverage: ONE persistent kernel, 128 blocks x 256 threads (all
// co-resident), device-scope grid barrier per iteration. Block s keeps its
// frame's occ row and a private covered bitmap in registers.
// ---------------------------------------------------------------------------
__device__ __forceinline__ void grid_barrier(unsigned* cnt, unsigned* gen) {
    __syncthreads();
    if (threadIdx.x == 0) {
        unsigned g = __hip_atomic_load(gen, __ATOMIC_RELAXED, __HIP_MEMORY_SCOPE_AGENT);
        unsigned a = __hip_atomic_fetch_add(cnt, 1u, __ATOMIC_ACQ_REL, __HIP_MEMORY_SCOPE_AGENT);
        if (a == (unsigned)S_FRAMES - 1u) {
            __hip_atomic_store(cnt, 0u, __ATOMIC_RELAXED, __HIP_MEMORY_SCOPE_AGENT);
            __hip_atomic_fetch_add(gen, 1u, __ATOMIC_RELEASE, __HIP_MEMORY_SCOPE_AGENT);
        } else {
            while (__hip_atomic_load(gen, __ATOMIC_ACQUIRE, __HIP_MEMORY_SCOPE_AGENT) == g)
                __builtin_amdgcn_s_sleep(1);
        }
    }
    __syncthreads();
}

__global__ __launch_bounds__(256) void greedy_kernel(unsigned* __restrict__ ws,
                                                     float* __restrict__ out) {
    const int s = blockIdx.x;
    const int tid = threadIdx.x;
    const unsigned* pA = ws + OCCA_OFF;
    const unsigned* pB = ws + OCCB_OFF;
    unsigned* key = ws + KEY_OFF;
    unsigned* bar = ws + BAR_OFF;

    unsigned occS[NWPT], covL[NWPT];
#pragma unroll
    for (int k = 0; k < NWPT; k++) {
        int w = tid + k * 256;
        occS[k] = (w < VWORDS) ? (pA[(unsigned)s * VWORDS + w] | pB[(unsigned)s * VWORDS + w]) : 0u;
        covL[k] = 0u;
    }

    __shared__ int wsum[4];
    __shared__ unsigned skk;
    unsigned sel0 = 0, sel1 = 0, sel2 = 0, sel3 = 0;  // 128-bit selected mask
    int best = -1;

    for (int it = 0; it < KSEL; it++) {
        if (best >= 0) {
            const unsigned* bA = pA + (unsigned)best * VWORDS;
            const unsigned* bB = pB + (unsigned)best * VWORDS;
#pragma unroll
            for (int k = 0; k < NWPT; k++) {
                int w = tid + k * 256;
                if (w < VWORDS) covL[k] |= bA[w] | bB[w];
            }
        }
        unsigned sm = (s < 32) ? sel0 : (s < 64) ? sel1 : (s < 96) ? sel2 : sel3;
        bool isSel = (sm >> (s & 31)) & 1u;
        if (!isSel) {
            int g = 0;
#pragma unroll
            for (int k = 0; k < NWPT; k++) g += __popc(occS[k] & ~covL[k]);
#pragma unroll
            for (int m = 32; m >= 1; m >>= 1) g += __shfl_xor(g, m);
            if ((tid & 63) == 0) wsum[tid >> 6] = g;
            __syncthreads();
            if (tid == 0) {
                g = wsum[0] + wsum[1] + wsum[2] + wsum[3];
                // key: max gain, then smallest s (jnp.argmax first-max tie-break)
                atomicMax(&key[it], ((unsigned)g << 7) | (unsigned)(127 - s));
            }
        }
        grid_barrier(bar, bar + 1);
        if (tid == 0) skk = __hip_atomic_load(&key[it], __ATOMIC_ACQUIRE, __HIP_MEMORY_SCOPE_AGENT);
        __syncthreads();
        unsigned kk = skk;
        best = 127 - (int)(kk & 127u);
        if (best < 32) sel0 |= 1u << best; else if (best < 64) sel1 |= 1u << (best & 31);
        else if (best < 96) sel2 |= 1u << (best & 31); else sel3 |= 1u << (best & 31);
        if (s == 0 && tid == 0) {
            out[it] = (float)best;
            out[KSEL + it] = (float)(kk >> 7);
        }
    }

    // total coverage: block 0 folds the last best and popcounts
    if (s == 0) {
        const unsigned* bA = pA + (unsigned)best * VWORDS;
        const unsigned* bB = pB + (unsigned)best * VWORDS;
        int t = 0;
#pragma unroll
        for (int k = 0; k < NWPT; k++) {
            int w = tid + k * 256;
            if (w < VWORDS) t += __popc(covL[k] | bA[w] | bB[w]);
        }
#pragma unroll
        for (int m = 32; m >= 1; m >>= 1) t += __shfl_xor(t, m);
        if ((tid & 63) == 0) wsum[tid >> 6] = t;
        __syncthreads();
        if (tid == 0) out[2 * KSEL] = (float)(wsum[0] + wsum[1] + wsum[2] + wsum[3]);
    }
}

extern "C" void kernel_launch(void* const* d_in, const int* in_sizes, int n_in,
                              void* d_out, int out_size, void* d_ws, size_t ws_size,
                              hipStream_t stream) {
    const float* wp   = (const float*)d_in[2];  // world_points [1,S,H,W,3]
    const float* conf = (const float*)d_in[3];  // world_points_conf [1,S,H,W]
    float* out = (float*)d_out;
    unsigned* ws = (unsigned*)d_ws;

    // zero only the control region: argmax keys, barrier, minmax slots
    hipMemsetAsync(ws + ZERO_OFF, 0, (size_t)ZERO_WORDS * 4, stream);

    float* pct = (float*)(ws + PCT_OFF);
    pct_kernel<<<128, 1024, 0, stream>>>(conf, pct);
    minmax_kernel<<<dim3(49, 128), 256, 0, stream>>>(wp, conf, pct, ws);
    voxel_kernel<<<256, 512, 0, stream>>>(wp, conf, pct, ws);
    greedy_kernel<<<128, 256, 0, stream>>>(ws, out);
}

// Round 4
// 266.084 us; speedup vs baseline: 1.5167x; 1.5167x over previous
//
#include <hip/hip_runtime.h>
#include <hip/hip_bf16.h>
#include <cstdint>

// Problem constants
#define S_FRAMES 128
#define HW       50176            // 224*224
#define NGRP     12544            // HW/4 float4 groups per frame
#define GDIM     48
#define VWORDS   3456             // 48^3 / 32 bits
#define NBINS    4096
#define CAP      512
#define KSEL     16

// greedy decomposition
#define GBLK     16               // blocks
#define FPB      8                // frames per block
#define GW       4                // occ words per thread (tid + k*1024)

// workspace layout (in 32-bit words)
#define OCCA_OFF  0u                          // 128 * 3456 words (part 0 bitmaps)
#define OCCB_OFF  (128u*3456u)                // 442368: part 1 bitmaps
#define SLOT_OFF  (2u*128u*3456u)             // 884736: 16 blocks x 32 words (own line each)
#define MM_OFF    (SLOT_OFF + 512u)           // 64 slots x 16 words (64B each)
#define PCT_OFF   (MM_OFF + 64u*16u)          // 128 floats
#define ZERO_OFF  SLOT_OFF
#define ZERO_WORDS (PCT_OFF - SLOT_OFF)       // slots + mm slots

__device__ __forceinline__ unsigned fkey(float f) {
    unsigned u = __float_as_uint(f);
    return (u & 0x80000000u) ? ~u : (u | 0x80000000u);
}
__device__ __forceinline__ float funkey(unsigned k) {
    unsigned u = (k & 0x80000000u) ? (k & 0x7fffffffu) : ~k;
    return __uint_as_float(u);
}

// ---------------------------------------------------------------------------
// Pass A: exact per-frame median (jnp.quantile 0.5 linear) via histogram select
// grid: 128 blocks (one per frame), 1024 threads, float4 loads both passes
// ---------------------------------------------------------------------------
__global__ __launch_bounds__(1024) void pct_kernel(const float* __restrict__ conf,
                                                   float* __restrict__ pct) {
    const int s = blockIdx.x;
    const int tid = threadIdx.x;
    const float4* c4 = (const float4*)(conf + (size_t)s * HW);

    __shared__ unsigned hist[NBINS];
    __shared__ unsigned ps[1024];
    __shared__ float    list[CAP];
    __shared__ unsigned cnt;
    __shared__ int      rbin[2];
    __shared__ unsigned rcum[2];
    __shared__ float    ab[2];

    for (int b = tid; b < NBINS; b += 1024) hist[b] = 0;
    if (tid == 0) cnt = 0;
    __syncthreads();

    for (int g = tid; g < NGRP; g += 1024) {
        float4 v = c4[g];
        int b0 = min(max((int)(v.x * 4096.0f), 0), NBINS - 1);
        int b1 = min(max((int)(v.y * 4096.0f), 0), NBINS - 1);
        int b2 = min(max((int)(v.z * 4096.0f), 0), NBINS - 1);
        int b3 = min(max((int)(v.w * 4096.0f), 0), NBINS - 1);
        atomicAdd(&hist[b0], 1u); atomicAdd(&hist[b1], 1u);
        atomicAdd(&hist[b2], 1u); atomicAdd(&hist[b3], 1u);
    }
    __syncthreads();

    // chunk sums (4 bins/thread) + inclusive scan over 1024 chunks
    unsigned chunk = hist[tid * 4] + hist[tid * 4 + 1] + hist[tid * 4 + 2] + hist[tid * 4 + 3];
    ps[tid] = chunk;
    __syncthreads();
    for (int off = 1; off < 1024; off <<= 1) {
        unsigned v = (tid >= off) ? ps[tid - off] : 0u;
        __syncthreads();
        ps[tid] += v;
        __syncthreads();
    }
    unsigned excl = ps[tid] - chunk;

    const unsigned R0 = 25087u, R1 = 25088u;  // 0.5*(50176-1) = 25087.5
#pragma unroll
    for (int r = 0; r < 2; r++) {
        unsigned rr = r ? R1 : R0;
        if (rr >= excl && rr < excl + chunk) {
            unsigned cum = excl;
            for (int j = 0; j < 4; j++) {
                unsigned h = hist[tid * 4 + j];
                if (rr < cum + h) { rbin[r] = tid * 4 + j; rcum[r] = cum; break; }
                cum += h;
            }
        }
    }
    __syncthreads();

    const int blo = rbin[0], bhi = rbin[1];
    const unsigned cumLo = rcum[0];

    for (int g = tid; g < NGRP; g += 1024) {
        float4 v = c4[g];
        float vv[4] = {v.x, v.y, v.z, v.w};
#pragma unroll
        for (int j = 0; j < 4; j++) {
            int b = min(max((int)(vv[j] * 4096.0f), 0), NBINS - 1);
            if (b >= blo && b <= bhi) {
                unsigned pos = atomicAdd(&cnt, 1u);
                if (pos < CAP) list[pos] = vv[j];
            }
        }
    }
    __syncthreads();

    const int n = (int)min(cnt, (unsigned)CAP);
    const int r0 = (int)(R0 - cumLo), r1 = (int)(R1 - cumLo);
    for (int e = tid; e < n; e += 1024) {
        float x = list[e];
        int rank = 0;
        for (int j = 0; j < n; j++) {
            float y = list[j];
            rank += (y < x) || (y == x && j < e);   // stable rank
        }
        if (rank == r0) ab[0] = x;
        if (rank == r1) ab[1] = x;
    }
    __syncthreads();
    if (tid == 0) pct[s] = 0.5f * ab[0] + 0.5f * ab[1];
}

// ---------------------------------------------------------------------------
// Pass B: global min/max over valid points. grid (49,128) x 256, 4 pts/thread.
// ---------------------------------------------------------------------------
__global__ __launch_bounds__(256) void minmax_kernel(const float* __restrict__ wp,
                                                     const float* __restrict__ conf,
                                                     const float* __restrict__ pct,
                                                     unsigned* __restrict__ ws) {
    const int s = blockIdx.y;
    const int tid = threadIdx.x;
    const int gidx = blockIdx.x * 256 + tid;        // [0, 12544)
    const float pc = pct[s];
    const size_t base = (size_t)s * HW;

    const float4 cf = ((const float4*)(conf + base))[gidx];
    const float4* wp4 = (const float4*)(wp + base * 3) + (size_t)gidx * 3;
    const float4 a = wp4[0], b = wp4[1], d = wp4[2];

    const float BIG = 3.402823466e38f;
    float mnx = BIG, mny = BIG, mnz = BIG;
    float mxx = -BIG, mxy = -BIG, mxz = -BIG;

    float px[4] = {a.x, a.w, b.z, d.y};
    float py[4] = {a.y, b.x, b.w, d.z};
    float pz[4] = {a.z, b.y, d.x, d.w};
    float cc[4] = {cf.x, cf.y, cf.z, cf.w};
#pragma unroll
    for (int j = 0; j < 4; j++) {
        bool v = (cc[j] > 0.1f) && (cc[j] >= pc);
        float x = v ? px[j] : BIG, y = v ? py[j] : BIG, z = v ? pz[j] : BIG;
        mnx = fminf(mnx, x); mny = fminf(mny, y); mnz = fminf(mnz, z);
        x = v ? px[j] : -BIG; y = v ? py[j] : -BIG; z = v ? pz[j] : -BIG;
        mxx = fmaxf(mxx, x); mxy = fmaxf(mxy, y); mxz = fmaxf(mxz, z);
    }
#pragma unroll
    for (int m = 32; m >= 1; m >>= 1) {
        mnx = fminf(mnx, __shfl_xor(mnx, m)); mny = fminf(mny, __shfl_xor(mny, m));
        mnz = fminf(mnz, __shfl_xor(mnz, m));
        mxx = fmaxf(mxx, __shfl_xor(mxx, m)); mxy = fmaxf(mxy, __shfl_xor(mxy, m));
        mxz = fmaxf(mxz, __shfl_xor(mxz, m));
    }
    __shared__ float red[4][6];
    if ((tid & 63) == 0) {
        int w = tid >> 6;
        red[w][0] = mnx; red[w][1] = mny; red[w][2] = mnz;
        red[w][3] = mxx; red[w][4] = mxy; red[w][5] = mxz;
    }
    __syncthreads();
    if (tid == 0) {
        float r0 = red[0][0], r1 = red[0][1], r2 = red[0][2];
        float r3 = red[0][3], r4 = red[0][4], r5 = red[0][5];
        for (int w = 1; w < 4; w++) {
            r0 = fminf(r0, red[w][0]); r1 = fminf(r1, red[w][1]); r2 = fminf(r2, red[w][2]);
            r3 = fmaxf(r3, red[w][3]); r4 = fmaxf(r4, red[w][4]); r5 = fmaxf(r5, red[w][5]);
        }
        unsigned* slot = ws + MM_OFF + (unsigned)((blockIdx.x + blockIdx.y * 49) & 63) * 16;
        atomicMax(slot + 0, fkey(-r0));   // min x  (as max of key(-x))
        atomicMax(slot + 1, fkey(-r1));
        atomicMax(slot + 2, fkey(-r2));
        atomicMax(slot + 3, fkey(r3));    // max x
        atomicMax(slot + 4, fkey(r4));
        atomicMax(slot + 5, fkey(r5));
    }
}

// ---------------------------------------------------------------------------
// Pass C: per-frame voxel occupancy. grid 256 (2 blocks/frame) x 512 threads.
// Each block plain-stores its half-frame bitmap to its own plane (occA/occB).
// ---------------------------------------------------------------------------
__global__ __launch_bounds__(512) void voxel_kernel(const float* __restrict__ wp,
                                                    const float* __restrict__ conf,
                                                    const float* __restrict__ pct,
                                                    unsigned* __restrict__ ws) {
    const int s = blockIdx.x >> 1;
    const int part = blockIdx.x & 1;
    const int tid = threadIdx.x;

    __shared__ unsigned bm[VWORDS];
    __shared__ float prm[4];  // pmx,pmy,pmz,vs
    for (int w = tid; w < VWORDS; w += 512) bm[w] = 0;

    if (tid < 64) {
        const unsigned* sl = ws + MM_OFF + (unsigned)tid * 16;
        unsigned k0 = sl[0], k1 = sl[1], k2 = sl[2], k3 = sl[3], k4 = sl[4], k5 = sl[5];
#pragma unroll
        for (int m = 32; m >= 1; m >>= 1) {
            k0 = max(k0, (unsigned)__shfl_xor((int)k0, m));
            k1 = max(k1, (unsigned)__shfl_xor((int)k1, m));
            k2 = max(k2, (unsigned)__shfl_xor((int)k2, m));
            k3 = max(k3, (unsigned)__shfl_xor((int)k3, m));
            k4 = max(k4, (unsigned)__shfl_xor((int)k4, m));
            k5 = max(k5, (unsigned)__shfl_xor((int)k5, m));
        }
        if (tid == 0) {
            float p0 = -funkey(k0), p1 = -funkey(k1), p2 = -funkey(k2);
            float d0 = funkey(k3) - p0, d1 = funkey(k4) - p1, d2 = funkey(k5) - p2;
            prm[0] = p0; prm[1] = p1; prm[2] = p2;
            prm[3] = fminf(d0, fminf(d1, d2)) / 20.0f;   // VOXEL_LAMBDA
        }
    }
    __syncthreads();

    const float pc = pct[s];
    const float pmx = prm[0], pmy = prm[1], pmz = prm[2], vs = prm[3];
    const size_t base = (size_t)s * HW;
    const float4* c4 = (const float4*)(conf + base);
    const float4* w4 = (const float4*)(wp + base * 3);

#pragma unroll 1
    for (int k = 0; k < 13; k++) {
        int gl = k * 512 + tid;                        // local group in half
        if (gl >= 6272) break;
        int g = part * 6272 + gl;
        float4 cf = c4[g];
        const float4* wg = w4 + (size_t)g * 3;
        float4 a = wg[0], b = wg[1], d = wg[2];
        float px[4] = {a.x, a.w, b.z, d.y};
        float py[4] = {a.y, b.x, b.w, d.z};
        float pz[4] = {a.z, b.y, d.x, d.w};
        float cc[4] = {cf.x, cf.y, cf.z, cf.w};
#pragma unroll
        for (int j = 0; j < 4; j++) {
            if (cc[j] > 0.1f && cc[j] >= pc) {
                int ix = min(max((int)floorf((px[j] - pmx) / vs), 0), GDIM - 1);
                int iy = min(max((int)floorf((py[j] - pmy) / vs), 0), GDIM - 1);
                int iz = min(max((int)floorf((pz[j] - pmz) / vs), 0), GDIM - 1);
                int vid = (ix * GDIM + iy) * GDIM + iz;
                atomicOr(&bm[vid >> 5], 1u << (vid & 31));
            }
        }
    }
    __syncthreads();

    unsigned* occ = ws + (part ? OCCB_OFF : OCCA_OFF) + (unsigned)s * VWORDS;
    for (int w = tid; w < VWORDS; w += 512) occ[w] = bm[w];
}

// ---------------------------------------------------------------------------
// Greedy max coverage: 16 blocks x 1024 threads, 8 frames/block in registers.
// No grid barrier: per-iteration all-gather via per-block private key slots
// (plain release store to own cache line, pollers read 16 distinct lines).
// ---------------------------------------------------------------------------
__global__ __launch_bounds__(1024) void greedy_kernel(unsigned* __restrict__ ws,
                                                      float* __restrict__ out) {
    const int b = blockIdx.x;
    const int tid = threadIdx.x;
    const int lane = tid & 63, wid = tid >> 6;
    const unsigned* pA = ws + OCCA_OFF;
    const unsigned* pB = ws + OCCB_OFF;
    unsigned* slots = ws + SLOT_OFF;         // slot(b,it) = b*32 + it

    unsigned occ[FPB][GW], cov[GW];
#pragma unroll
    for (int k = 0; k < GW; k++) cov[k] = 0u;
#pragma unroll
    for (int j = 0; j < FPB; j++) {
        unsigned f = (unsigned)(b * FPB + j);
#pragma unroll
        for (int k = 0; k < GW; k++) {
            int w = tid + k * 1024;
            occ[j][k] = (w < VWORDS) ? (pA[f * VWORDS + w] | pB[f * VWORDS + w]) : 0u;
        }
    }

    __shared__ int part[16][FPB];
    __shared__ unsigned keysh[FPB];
    __shared__ unsigned bbc;
    unsigned selMask = 0;
    int best = -1;

    for (int it = 0; it < KSEL; it++) {
        if (best >= 0) {
            const unsigned* bA = pA + (unsigned)best * VWORDS;
            const unsigned* bB = pB + (unsigned)best * VWORDS;
#pragma unroll
            for (int k = 0; k < GW; k++) {
                int w = tid + k * 1024;
                if (w < VWORDS) cov[k] |= bA[w] | bB[w];
            }
        }
        // per-frame gains: popc(occ & ~cov), wave-reduce, stash per-wave partials
#pragma unroll
        for (int j = 0; j < FPB; j++) {
            int g = 0;
#pragma unroll
            for (int k = 0; k < GW; k++) g += __popc(occ[j][k] & ~cov[k]);
#pragma unroll
            for (int m = 32; m >= 1; m >>= 1) g += __shfl_xor(g, m);
            if (lane == 0) part[wid][j] = g;
        }
        __syncthreads();
        if (tid < FPB) {
            int g = 0;
            for (int w = 0; w < 16; w++) g += part[w][tid];
            int f = b * FPB + tid;
            // key: max gain, then smallest s (jnp.argmax first-max tie-break)
            keysh[tid] = ((selMask >> tid) & 1u) ? 0u
                       : (((unsigned)g << 7) | (unsigned)(127 - f));
        }
        __syncthreads();
        if (tid == 0) {
            unsigned kb = 0;
#pragma unroll
            for (int j = 0; j < FPB; j++) kb = max(kb, keysh[j]);
            __hip_atomic_store(&slots[b * 32 + it], kb | 0x80000000u,
                               __ATOMIC_RELEASE, __HIP_MEMORY_SCOPE_AGENT);
        }
        // all-gather: 16 lanes poll 16 private lines until valid, then max
        if (tid < GBLK) {
            unsigned v;
            do {
                v = __hip_atomic_load(&slots[tid * 32 + it],
                                      __ATOMIC_ACQUIRE, __HIP_MEMORY_SCOPE_AGENT);
            } while (!(v & 0x80000000u));
            unsigned p = v & 0x7fffffffu;
#pragma unroll
            for (int m = 8; m >= 1; m >>= 1) p = max(p, (unsigned)__shfl_xor((int)p, m));
            if (tid == 0) bbc = p;
        }
        __syncthreads();
        unsigned kk = bbc;
        __syncthreads();
        best = 127 - (int)(kk & 127u);
        if (best >= b * FPB && best < (b + 1) * FPB) selMask |= 1u << (best - b * FPB);
        if (b == 0 && tid == 0) {
            out[it] = (float)best;
            out[KSEL + it] = (float)(kk >> 7);
        }
    }

    // total coverage: block 0 folds the last best and popcounts
    if (b == 0) {
        const unsigned* bA = pA + (unsigned)best * VWORDS;
        const unsigned* bB = pB + (unsigned)best * VWORDS;
        int t = 0;
#pragma unroll
        for (int k = 0; k < GW; k++) {
            int w = tid + k * 1024;
            if (w < VWORDS) t += __popc(cov[k] | bA[w] | bB[w]);
        }
#pragma unroll
        for (int m = 32; m >= 1; m >>= 1) t += __shfl_xor(t, m);
        if (lane == 0) part[wid][0] = t;
        __syncthreads();
        if (tid == 0) {
            int tt = 0;
            for (int w = 0; w < 16; w++) tt += part[w][0];
            out[2 * KSEL] = (float)tt;
        }
    }
}

extern "C" void kernel_launch(void* const* d_in, const int* in_sizes, int n_in,
                              void* d_out, int out_size, void* d_ws, size_t ws_size,
                              hipStream_t stream) {
    const float* wp   = (const float*)d_in[2];  // world_points [1,S,H,W,3]
    const float* conf = (const float*)d_in[3];  // world_points_conf [1,S,H,W]
    float* out = (float*)d_out;
    unsigned* ws = (unsigned*)d_ws;

    // zero only the control region: key slots + minmax slots
    hipMemsetAsync(ws + ZERO_OFF, 0, (size_t)ZERO_WORDS * 4, stream);

    float* pct = (float*)(ws + PCT_OFF);
    pct_kernel<<<128, 1024, 0, stream>>>(conf, pct);
    minmax_kernel<<<dim3(49, 128), 256, 0, stream>>>(wp, conf, pct, ws);
    voxel_kernel<<<256, 512, 0, stream>>>(wp, conf, pct, ws);
    greedy_kernel<<<GBLK, 1024, 0, stream>>>(ws, out);
}

// Round 5
// 261.068 us; speedup vs baseline: 1.5459x; 1.0192x over previous
//
#include <hip/hip_runtime.h>
#include <hip/hip_bf16.h>
#include <cstdint>

// Problem constants
#define S_FRAMES 128
#define HW       50176            // 224*224
#define NGRP     12544            // HW/4 float4 groups per frame
#define GDIM     48
#define VWORDS   3456             // 48^3 / 32 bits
#define NBINS    4096
#define CAP      512
#define KSEL     16

// greedy decomposition
#define GBLK     16               // blocks
#define FPB      8                // frames per block
#define GW       4                // occ words per thread (tid + k*1024)

// workspace layout (in 32-bit words)
#define OCCA_OFF  0u                          // 128 * 3456 words (part 0 bitmaps)
#define OCCB_OFF  (128u*3456u)                // 442368: part 1 bitmaps
#define SLOT_OFF  (2u*128u*3456u)             // 884736: 16 blocks x 32 words (own lines)
#define MM_OFF    (SLOT_OFF + 512u)           // 64 slots x 16 words (64B each)
#define PCT_OFF   (MM_OFF + 64u*16u)          // 128 floats
#define ZERO_OFF  SLOT_OFF
#define ZERO_WORDS (PCT_OFF - SLOT_OFF)       // slots + mm slots

__device__ __forceinline__ unsigned fkey(float f) {
    unsigned u = __float_as_uint(f);
    return (u & 0x80000000u) ? ~u : (u | 0x80000000u);
}
__device__ __forceinline__ float funkey(unsigned k) {
    unsigned u = (k & 0x80000000u) ? (k & 0x7fffffffu) : ~k;
    return __uint_as_float(u);
}

// ---------------------------------------------------------------------------
// Pass A: exact per-frame median (jnp.quantile 0.5 linear) via histogram select
// grid: 128 blocks (one per frame), 1024 threads, float4 loads both passes.
// Prefix scan = shfl wave-scan + wave-offset scan (2 barriers).
// ---------------------------------------------------------------------------
__global__ __launch_bounds__(1024) void pct_kernel(const float* __restrict__ conf,
                                                   float* __restrict__ pct) {
    const int s = blockIdx.x;
    const int tid = threadIdx.x;
    const int lane = tid & 63, wid = tid >> 6;
    const float4* c4 = (const float4*)(conf + (size_t)s * HW);

    __shared__ unsigned hist[NBINS];
    __shared__ unsigned wtot[16];
    __shared__ unsigned woff[16];
    __shared__ float    list[CAP];
    __shared__ unsigned cnt;
    __shared__ int      rbin[2];
    __shared__ unsigned rcum[2];
    __shared__ float    ab[2];

    for (int b = tid; b < NBINS; b += 1024) hist[b] = 0;
    if (tid == 0) cnt = 0;
    __syncthreads();

    for (int g = tid; g < NGRP; g += 1024) {
        float4 v = c4[g];
        int b0 = min(max((int)(v.x * 4096.0f), 0), NBINS - 1);
        int b1 = min(max((int)(v.y * 4096.0f), 0), NBINS - 1);
        int b2 = min(max((int)(v.z * 4096.0f), 0), NBINS - 1);
        int b3 = min(max((int)(v.w * 4096.0f), 0), NBINS - 1);
        atomicAdd(&hist[b0], 1u); atomicAdd(&hist[b1], 1u);
        atomicAdd(&hist[b2], 1u); atomicAdd(&hist[b3], 1u);
    }
    __syncthreads();

    // chunk sums (4 bins/thread) + exclusive scan over 1024 chunks
    unsigned chunk = hist[tid * 4] + hist[tid * 4 + 1] + hist[tid * 4 + 2] + hist[tid * 4 + 3];
    unsigned x = chunk;
#pragma unroll
    for (int m = 1; m < 64; m <<= 1) {
        unsigned y = (unsigned)__shfl_up((int)x, m);
        if (lane >= m) x += y;
    }
    if (lane == 63) wtot[wid] = x;
    __syncthreads();
    if (tid < 16) {
        unsigned acc = 0;
        for (int w = 0; w < tid; w++) acc += wtot[w];
        woff[tid] = acc;
    }
    __syncthreads();
    unsigned excl = x - chunk + woff[wid];

    const unsigned R0 = 25087u, R1 = 25088u;  // 0.5*(50176-1) = 25087.5
#pragma unroll
    for (int r = 0; r < 2; r++) {
        unsigned rr = r ? R1 : R0;
        if (rr >= excl && rr < excl + chunk) {
            unsigned cum = excl;
            for (int j = 0; j < 4; j++) {
                unsigned h = hist[tid * 4 + j];
                if (rr < cum + h) { rbin[r] = tid * 4 + j; rcum[r] = cum; break; }
                cum += h;
            }
        }
    }
    __syncthreads();

    const int blo = rbin[0], bhi = rbin[1];
    const unsigned cumLo = rcum[0];

    for (int g = tid; g < NGRP; g += 1024) {
        float4 v = c4[g];
        float vv[4] = {v.x, v.y, v.z, v.w};
#pragma unroll
        for (int j = 0; j < 4; j++) {
            int b = min(max((int)(vv[j] * 4096.0f), 0), NBINS - 1);
            if (b >= blo && b <= bhi) {
                unsigned pos = atomicAdd(&cnt, 1u);
                if (pos < CAP) list[pos] = vv[j];
            }
        }
    }
    __syncthreads();

    const int n = (int)min(cnt, (unsigned)CAP);
    const int r0 = (int)(R0 - cumLo), r1 = (int)(R1 - cumLo);
    for (int e = tid; e < n; e += 1024) {
        float xx = list[e];
        int rank = 0;
        for (int j = 0; j < n; j++) {
            float y = list[j];
            rank += (y < xx) || (y == xx && j < e);   // stable rank
        }
        if (rank == r0) ab[0] = xx;
        if (rank == r1) ab[1] = xx;
    }
    __syncthreads();
    if (tid == 0) pct[s] = 0.5f * ab[0] + 0.5f * ab[1];
}

// ---------------------------------------------------------------------------
// Pass B: global min/max over valid points. grid (49,128) x 256, 4 pts/thread.
// ---------------------------------------------------------------------------
__global__ __launch_bounds__(256) void minmax_kernel(const float* __restrict__ wp,
                                                     const float* __restrict__ conf,
                                                     const float* __restrict__ pct,
                                                     unsigned* __restrict__ ws) {
    const int s = blockIdx.y;
    const int tid = threadIdx.x;
    const int gidx = blockIdx.x * 256 + tid;        // [0, 12544)
    const float pc = pct[s];
    const size_t base = (size_t)s * HW;

    const float4 cf = ((const float4*)(conf + base))[gidx];
    const float4* wp4 = (const float4*)(wp + base * 3) + (size_t)gidx * 3;
    const float4 a = wp4[0], b = wp4[1], d = wp4[2];

    const float BIG = 3.402823466e38f;
    float mnx = BIG, mny = BIG, mnz = BIG;
    float mxx = -BIG, mxy = -BIG, mxz = -BIG;

    float px[4] = {a.x, a.w, b.z, d.y};
    float py[4] = {a.y, b.x, b.w, d.z};
    float pz[4] = {a.z, b.y, d.x, d.w};
    float cc[4] = {cf.x, cf.y, cf.z, cf.w};
#pragma unroll
    for (int j = 0; j < 4; j++) {
        bool v = (cc[j] > 0.1f) && (cc[j] >= pc);
        float x = v ? px[j] : BIG, y = v ? py[j] : BIG, z = v ? pz[j] : BIG;
        mnx = fminf(mnx, x); mny = fminf(mny, y); mnz = fminf(mnz, z);
        x = v ? px[j] : -BIG; y = v ? py[j] : -BIG; z = v ? pz[j] : -BIG;
        mxx = fmaxf(mxx, x); mxy = fmaxf(mxy, y); mxz = fmaxf(mxz, z);
    }
#pragma unroll
    for (int m = 32; m >= 1; m >>= 1) {
        mnx = fminf(mnx, __shfl_xor(mnx, m)); mny = fminf(mny, __shfl_xor(mny, m));
        mnz = fminf(mnz, __shfl_xor(mnz, m));
        mxx = fmaxf(mxx, __shfl_xor(mxx, m)); mxy = fmaxf(mxy, __shfl_xor(mxy, m));
        mxz = fmaxf(mxz, __shfl_xor(mxz, m));
    }
    __shared__ float red[4][6];
    if ((tid & 63) == 0) {
        int w = tid >> 6;
        red[w][0] = mnx; red[w][1] = mny; red[w][2] = mnz;
        red[w][3] = mxx; red[w][4] = mxy; red[w][5] = mxz;
    }
    __syncthreads();
    if (tid == 0) {
        float r0 = red[0][0], r1 = red[0][1], r2 = red[0][2];
        float r3 = red[0][3], r4 = red[0][4], r5 = red[0][5];
        for (int w = 1; w < 4; w++) {
            r0 = fminf(r0, red[w][0]); r1 = fminf(r1, red[w][1]); r2 = fminf(r2, red[w][2]);
            r3 = fmaxf(r3, red[w][3]); r4 = fmaxf(r4, red[w][4]); r5 = fmaxf(r5, red[w][5]);
        }
        unsigned* slot = ws + MM_OFF + (unsigned)((blockIdx.x + blockIdx.y * 49) & 63) * 16;
        atomicMax(slot + 0, fkey(-r0));   // min x  (as max of key(-x))
        atomicMax(slot + 1, fkey(-r1));
        atomicMax(slot + 2, fkey(-r2));
        atomicMax(slot + 3, fkey(r3));    // max x
        atomicMax(slot + 4, fkey(r4));
        atomicMax(slot + 5, fkey(r5));
    }
}

// ---------------------------------------------------------------------------
// Pass C: per-frame voxel occupancy. grid 256 (2 blocks/frame) x 512 threads.
// Each block plain-stores its half-frame bitmap to its own plane (occA/occB).
// ---------------------------------------------------------------------------
__global__ __launch_bounds__(512) void voxel_kernel(const float* __restrict__ wp,
                                                    const float* __restrict__ conf,
                                                    const float* __restrict__ pct,
                                                    unsigned* __restrict__ ws) {
    const int s = blockIdx.x >> 1;
    const int part = blockIdx.x & 1;
    const int tid = threadIdx.x;

    __shared__ unsigned bm[VWORDS];
    __shared__ float prm[4];  // pmx,pmy,pmz,vs
    for (int w = tid; w < VWORDS; w += 512) bm[w] = 0;

    if (tid < 64) {
        const unsigned* sl = ws + MM_OFF + (unsigned)tid * 16;
        unsigned k0 = sl[0], k1 = sl[1], k2 = sl[2], k3 = sl[3], k4 = sl[4], k5 = sl[5];
#pragma unroll
        for (int m = 32; m >= 1; m >>= 1) {
            k0 = max(k0, (unsigned)__shfl_xor((int)k0, m));
            k1 = max(k1, (unsigned)__shfl_xor((int)k1, m));
            k2 = max(k2, (unsigned)__shfl_xor((int)k2, m));
            k3 = max(k3, (unsigned)__shfl_xor((int)k3, m));
            k4 = max(k4, (unsigned)__shfl_xor((int)k4, m));
            k5 = max(k5, (unsigned)__shfl_xor((int)k5, m));
        }
        if (tid == 0) {
            float p0 = -funkey(k0), p1 = -funkey(k1), p2 = -funkey(k2);
            float d0 = funkey(k3) - p0, d1 = funkey(k4) - p1, d2 = funkey(k5) - p2;
            prm[0] = p0; prm[1] = p1; prm[2] = p2;
            prm[3] = fminf(d0, fminf(d1, d2)) / 20.0f;   // VOXEL_LAMBDA
        }
    }
    __syncthreads();

    const float pc = pct[s];
    const float pmx = prm[0], pmy = prm[1], pmz = prm[2], vs = prm[3];
    const size_t base = (size_t)s * HW;
    const float4* c4 = (const float4*)(conf + base);
    const float4* w4 = (const float4*)(wp + base * 3);

#pragma unroll 1
    for (int k = 0; k < 13; k++) {
        int gl = k * 512 + tid;                        // local group in half
        if (gl >= 6272) break;
        int g = part * 6272 + gl;
        float4 cf = c4[g];
        const float4* wg = w4 + (size_t)g * 3;
        float4 a = wg[0], b = wg[1], d = wg[2];
        float px[4] = {a.x, a.w, b.z, d.y};
        float py[4] = {a.y, b.x, b.w, d.z};
        float pz[4] = {a.z, b.y, d.x, d.w};
        float cc[4] = {cf.x, cf.y, cf.z, cf.w};
#pragma unroll
        for (int j = 0; j < 4; j++) {
            if (cc[j] > 0.1f && cc[j] >= pc) {
                int ix = min(max((int)floorf((px[j] - pmx) / vs), 0), GDIM - 1);
                int iy = min(max((int)floorf((py[j] - pmy) / vs), 0), GDIM - 1);
                int iz = min(max((int)floorf((pz[j] - pmz) / vs), 0), GDIM - 1);
                int vid = (ix * GDIM + iy) * GDIM + iz;
                atomicOr(&bm[vid >> 5], 1u << (vid & 31));
            }
        }
    }
    __syncthreads();

    unsigned* occ = ws + (part ? OCCB_OFF : OCCA_OFF) + (unsigned)s * VWORDS;
    for (int w = tid; w < VWORDS; w += 512) occ[w] = bm[w];
}

// ---------------------------------------------------------------------------
// Greedy max coverage: 16 blocks x 1024 threads, 8 frames/block in registers.
// All-gather via per-block private key slots. The slot word IS the whole
// message (valid bit | key) => RELAXED atomics suffice: no acquire invalidates,
// no release writebacks. 2 __syncthreads per iteration.
// ---------------------------------------------------------------------------
__global__ __launch_bounds__(1024) void greedy_kernel(unsigned* __restrict__ ws,
                                                      float* __restrict__ out) {
    const int b = blockIdx.x;
    const int tid = threadIdx.x;
    const int lane = tid & 63, wid = tid >> 6;
    const unsigned* pA = ws + OCCA_OFF;
    const unsigned* pB = ws + OCCB_OFF;
    unsigned* slots = ws + SLOT_OFF;         // slot(b,it) = b*32 + it

    unsigned occ[FPB][GW], cov[GW];
#pragma unroll
    for (int k = 0; k < GW; k++) cov[k] = 0u;
#pragma unroll
    for (int j = 0; j < FPB; j++) {
        unsigned f = (unsigned)(b * FPB + j);
#pragma unroll
        for (int k = 0; k < GW; k++) {
            int w = tid + k * 1024;
            occ[j][k] = (w < VWORDS) ? (pA[f * VWORDS + w] | pB[f * VWORDS + w]) : 0u;
        }
    }

    __shared__ int part[16][FPB];
    __shared__ unsigned bbc;
    unsigned selMask = 0;
    int best = -1;

    for (int it = 0; it < KSEL; it++) {
        if (best >= 0) {
            const unsigned* bA = pA + (unsigned)best * VWORDS;
            const unsigned* bB = pB + (unsigned)best * VWORDS;
#pragma unroll
            for (int k = 0; k < GW; k++) {
                int w = tid + k * 1024;
                if (w < VWORDS) cov[k] |= bA[w] | bB[w];
            }
        }
        // per-frame gains: popc(occ & ~cov), wave-reduce, stash per-wave partials
#pragma unroll
        for (int j = 0; j < FPB; j++) {
            int g = 0;
#pragma unroll
            for (int k = 0; k < GW; k++) g += __popc(occ[j][k] & ~cov[k]);
#pragma unroll
            for (int m = 32; m >= 1; m >>= 1) g += __shfl_xor(g, m);
            if (lane == 0) part[wid][j] = g;
        }
        __syncthreads();
        // wave 0: build block key, publish, poll all 16 slots, broadcast
        if (wid == 0) {
            unsigned key = 0;
            if (lane < FPB) {
                int g = 0;
#pragma unroll
                for (int w = 0; w < 16; w++) g += part[w][lane];
                int f = b * FPB + lane;
                // key: max gain, then smallest s (jnp.argmax first-max tie-break)
                key = ((selMask >> lane) & 1u) ? 0u
                    : (((unsigned)g << 7) | (unsigned)(127 - f));
            }
#pragma unroll
            for (int m = 4; m >= 1; m >>= 1) key = max(key, (unsigned)__shfl_xor((int)key, m));
            if (lane == 0)
                __hip_atomic_store(&slots[b * 32 + it], key | 0x80000000u,
                                   __ATOMIC_RELAXED, __HIP_MEMORY_SCOPE_AGENT);
            unsigned p = 0;
            if (lane < GBLK) {
                unsigned v;
                do {
                    v = __hip_atomic_load(&slots[lane * 32 + it],
                                          __ATOMIC_RELAXED, __HIP_MEMORY_SCOPE_AGENT);
                } while (!(v & 0x80000000u));
                p = v & 0x7fffffffu;
            }
#pragma unroll
            for (int m = 8; m >= 1; m >>= 1) p = max(p, (unsigned)__shfl_xor((int)p, m));
            if (lane == 0) bbc = p;
        }
        __syncthreads();
        unsigned kk = bbc;
        best = 127 - (int)(kk & 127u);
        if (best >= b * FPB && best < (b + 1) * FPB) selMask |= 1u << (best - b * FPB);
        if (b == 0 && tid == 0) {
            out[it] = (float)best;
            out[KSEL + it] = (float)(kk >> 7);
        }
        __syncthreads();   // protect part[]/bbc reuse next iteration
    }

    // total coverage: block 0 folds the last best and popcounts
    if (b == 0) {
        const unsigned* bA = pA + (unsigned)best * VWORDS;
        const unsigned* bB = pB + (unsigned)best * VWORDS;
        int t = 0;
#pragma unroll
        for (int k = 0; k < GW; k++) {
            int w = tid + k * 1024;
            if (w < VWORDS) t += __popc(cov[k] | bA[w] | bB[w]);
        }
#pragma unroll
        for (int m = 32; m >= 1; m >>= 1) t += __shfl_xor(t, m);
        if (lane == 0) part[wid][0] = t;
        __syncthreads();
        if (tid == 0) {
            int tt = 0;
            for (int w = 0; w < 16; w++) tt += part[w][0];
            out[2 * KSEL] = (float)tt;
        }
    }
}

extern "C" void kernel_launch(void* const* d_in, const int* in_sizes, int n_in,
                              void* d_out, int out_size, void* d_ws, size_t ws_size,
                              hipStream_t stream) {
    const float* wp   = (const float*)d_in[2];  // world_points [1,S,H,W,3]
    const float* conf = (const float*)d_in[3];  // world_points_conf [1,S,H,W]
    float* out = (float*)d_out;
    unsigned* ws = (unsigned*)d_ws;

    // zero only the control region: key slots + minmax slots
    hipMemsetAsync(ws + ZERO_OFF, 0, (size_t)ZERO_WORDS * 4, stream);

    float* pct = (float*)(ws + PCT_OFF);
    pct_kernel<<<128, 1024, 0, stream>>>(conf, pct);
    minmax_kernel<<<dim3(49, 128), 256, 0, stream>>>(wp, conf, pct, ws);
    voxel_kernel<<<256, 512, 0, stream>>>(wp, conf, pct, ws);
    greedy_kernel<<<GBLK, 1024, 0, stream>>>(ws, out);
}